// Round 16
// baseline (143.282 us; speedup 1.0000x reference)
//
#include <hip/hip_runtime.h>
#include <hip/hip_bf16.h>
#include <stdint.h>

typedef unsigned short u16;
typedef short short8 __attribute__((ext_vector_type(8)));
typedef float f32x4 __attribute__((ext_vector_type(4)));
typedef u16 u16x4 __attribute__((ext_vector_type(4)));

#define SCLOG 0.18033688011112042f  // 0.125 * log2(e)

static __device__ __forceinline__ u16 f2bf(float f) {
  unsigned u = __float_as_uint(f);
  unsigned rnd = 0x7fffu + ((u >> 16) & 1u);
  return (u16)((u + rnd) >> 16);
}

// packed f32x2 -> bf16x2 via HW v_cvt_pk_bf16_f32 (no builtin on gfx950; T12/m240)
static __device__ __forceinline__ unsigned pk_bf16(float a, float b) {
  unsigned r;
  asm("v_cvt_pk_bf16_f32 %0, %1, %2" : "=v"(r) : "v"(a), "v"(b));
  return r;
}

static __device__ __forceinline__ void gload_lds16(const void* g, void* l) {
  __builtin_amdgcn_global_load_lds(
      (const __attribute__((address_space(1))) unsigned int*)g,
      (__attribute__((address_space(3))) unsigned int*)l, 16, 0, 0);
}

// ---------------------------------------------------------------- fused prep
__global__ __launch_bounds__(256) void prep_kernel(
    const float* __restrict__ hs, const int* __restrict__ mask,
    const float* __restrict__ Wq, const float* __restrict__ Wk,
    const float* __restrict__ Wv, const float* __restrict__ Wo,
    u16* __restrict__ X, u16* __restrict__ WT,
    unsigned long long* __restrict__ bits) {
  __shared__ float tile[32][33];
  const int bid = blockIdx.x;
  const int tid = threadIdx.x;
  if (bid < 4096) {
    const int i = bid * 256 + tid;
    const float4 v = reinterpret_cast<const float4*>(hs)[i];
    u16x4 o;
    o[0] = f2bf(v.x); o[1] = f2bf(v.y); o[2] = f2bf(v.z); o[3] = f2bf(v.w);
    reinterpret_cast<u16x4*>(X)[i] = o;
  } else if (bid < 8192) {
    const int B = bid - 4096;
    const int z = B >> 10, y = (B >> 5) & 31, x = B & 31;
    const float* src = (z == 0) ? Wq : (z == 1) ? Wk : (z == 2) ? Wv : Wo;
    u16* dst = WT + (size_t)z * 1024 * 1024;
    const int row0 = y * 32, col0 = x * 32;
    const int tx = tid & 31, ty = tid >> 5;
#pragma unroll
    for (int i = 0; i < 4; ++i)
      tile[ty + i * 8][tx] = src[(size_t)(row0 + ty + i * 8) * 1024 + col0 + tx];
    __syncthreads();
#pragma unroll
    for (int i = 0; i < 4; ++i) {
      const int r = ty + i * 8;
      dst[(size_t)(col0 + r) * 1024 + row0 + tx] = f2bf(tile[tx][r]);
    }
  } else {
    const int gw = (bid - 8192) * 4 + (tid >> 6);
    const int lane = tid & 63;
    const int q = gw >> 5, w = gw & 31;
    const int mv = mask[(size_t)q * 2048 + w * 64 + lane];
    const unsigned long long bal = __ballot(mv != 0);
    if (lane == 0) bits[(size_t)q * 32 + w] = bal;
  }
}

// ---------------------------------------------------------------- GEMM QKV
// BK=32 + XCD swizzle + T3 minimum 2-phase double-buffer: stage kt+1 into
// buf^1 BEFORE compute of buf; one barrier per K-step (loads fly under MFMA).
__global__ __launch_bounds__(256) void gemm_qkv_kernel(
    const u16* __restrict__ X, const u16* __restrict__ WT,
    const float* __restrict__ bq, const float* __restrict__ bk, const float* __restrict__ bv,
    u16* __restrict__ Qb, u16* __restrict__ Kb, u16* __restrict__ Vb) {
  __shared__ u16 As[2][128 * 32];
  __shared__ u16 Bs[2][128 * 32];
  const int tid = threadIdx.x;
  const int lane = tid & 63, wid = tid >> 6;
  const int l15 = lane & 15, lg = lane >> 4;
  const int wg = blockIdx.x;            // 768 = 8 XCDs x (3 n-panels x 32 m)
  const int xcd = wg & 7, idx = wg >> 3;
  const int n0 = (xcd * 3 + (idx >> 5)) * 128;
  const int m0 = (idx & 31) * 128;
  const int wr = wid >> 1, wc = wid & 1;

  f32x4 acc[4][4] = {};

#define QKV_STAGE(bb, ktv)                                                \
  do {                                                                    \
    _Pragma("unroll") for (int p_ = 0; p_ < 2; ++p_) {                    \
      const int c_ = p_ * 256 + tid;                                      \
      const int r_ = c_ >> 2, ch_ = c_ & 3;                               \
      gload_lds16(X + (size_t)(m0 + r_) * 1024 + (ktv) * 32 + ch_ * 8,    \
                  &As[bb][(p_ * 256 + wid * 64) * 8]);                    \
      gload_lds16(WT + (size_t)(n0 + r_) * 1024 + (ktv) * 32 + ch_ * 8,   \
                  &Bs[bb][(p_ * 256 + wid * 64) * 8]);                    \
    }                                                                     \
  } while (0)

  QKV_STAGE(0, 0);
  __syncthreads();
  int buf = 0;

  for (int kt = 0; kt < 32; ++kt) {
    if (kt < 31) QKV_STAGE(buf ^ 1, kt + 1);
    short8 af[4], bfr[4];
#pragma unroll
    for (int i = 0; i < 4; ++i) {
      af[i] = *reinterpret_cast<const short8*>(&As[buf][(wr * 64 + i * 16 + l15) * 32 + lg * 8]);
      bfr[i] = *reinterpret_cast<const short8*>(&Bs[buf][(wc * 64 + i * 16 + l15) * 32 + lg * 8]);
    }
#pragma unroll
    for (int i = 0; i < 4; ++i)
#pragma unroll
      for (int j = 0; j < 4; ++j)
        acc[i][j] = __builtin_amdgcn_mfma_f32_16x16x32_bf16(bfr[j], af[i], acc[i][j], 0, 0, 0);
    __syncthreads();
    buf ^= 1;
  }
#undef QKV_STAGE

#pragma unroll
  for (int i = 0; i < 4; ++i) {
    const int m = m0 + wr * 64 + i * 16 + l15;
    const int bb = m >> 11, t = m & 2047;
#pragma unroll
    for (int j = 0; j < 4; ++j) {
      const int n = n0 + wc * 64 + j * 16 + lg * 4;
      const float* bsrc = (n < 1024) ? (bq + n) : (n < 2048) ? (bk + n - 1024) : (bv + n - 2048);
      const float4 b4 = *reinterpret_cast<const float4*>(bsrc);
      const float scl = (n < 1024) ? SCLOG : 1.0f;
      u16* dst = (n < 1024) ? Qb : (n < 2048) ? Kb : Vb;
      const int nl = n & 1023;
      const int hh = nl >> 6, d0 = nl & 63;
      uint2 pk;
      pk.x = pk_bf16((acc[i][j][0] + b4.x) * scl, (acc[i][j][1] + b4.y) * scl);
      pk.y = pk_bf16((acc[i][j][2] + b4.z) * scl, (acc[i][j][3] + b4.w) * scl);
      *reinterpret_cast<uint2*>(dst + ((size_t)(bb * 16 + hh) * 2048 + t) * 64 + d0) = pk;
    }
  }
}

// ------------------------------------------------------------ V transpose
__global__ __launch_bounds__(256) void transpose_v_kernel(const u16* __restrict__ Vb,
                                                          u16* __restrict__ VT) {
  __shared__ u16 tile[64][68];
  const int tid = threadIdx.x;
  const int tt = blockIdx.x & 31;
  const int bh = blockIdx.x >> 5;
  const size_t base = (size_t)bh * 2048 * 64;
  const int t0 = tt * 64;
#pragma unroll
  for (int p = 0; p < 2; ++p) {
    int i = p * 256 + tid;
    int row = i >> 3, ch = i & 7;
    *reinterpret_cast<short8*>(&tile[row][ch * 8]) =
        *reinterpret_cast<const short8*>(Vb + base + (size_t)(t0 + row) * 64 + ch * 8);
  }
  __syncthreads();
#pragma unroll
  for (int p = 0; p < 2; ++p) {
    int i = p * 256 + tid;
    int d = i >> 3, ch = i & 7;
    short8 v;
#pragma unroll
    for (int j = 0; j < 8; ++j) v[j] = tile[ch * 8 + j][d];
    *reinterpret_cast<short8*>(VT + base + (size_t)d * 2048 + t0 + ch * 8) = v;
  }
}

// ---------------------------------------------------------------- attention
// (R10/R12 version — frozen session optimum. Max-free softmax, 4 waves/block,
// paired 32-row q-tiles, double-buffered LDS staging, grid 1024.)
struct AttnState {
  f32x4 O[4];
  float l;        // per-lane partial (reduced at epilogue)
  short8 qf0, qf1;
};

static __device__ __forceinline__ void attn_tile(
    AttnState& st, const u16* __restrict__ Kb_, const u16* __restrict__ Vb_,
    u16* __restrict__ pwave, unsigned long long w,
    int l15, int lg, int slg) {
  f32x4 sT[4] = {};
  __builtin_amdgcn_s_setprio(1);
#pragma unroll
  for (int dc = 0; dc < 2; ++dc) {
    const short8 qv = dc ? st.qf1 : st.qf0;
#pragma unroll
    for (int sub = 0; sub < 4; ++sub) {
      const short8 kf = *reinterpret_cast<const short8*>(
          &Kb_[dc * 2048 + (sub * 16 + l15) * 32 + slg]);
      sT[sub] = __builtin_amdgcn_mfma_f32_16x16x32_bf16(kf, qv, sT[sub], 0, 0, 0);
    }
  }
  __builtin_amdgcn_s_setprio(0);

  if (!__all(w == ~0ull)) {
    const unsigned mlo = (unsigned)w, mhi = (unsigned)(w >> 32);
#pragma unroll
    for (int sub = 0; sub < 4; ++sub) {
      const unsigned f = ((sub & 2) ? mhi : mlo) >> ((sub & 1) * 16 + lg * 4);
#pragma unroll
      for (int r = 0; r < 4; ++r)
        sT[sub][r] = ((f >> r) & 1u) ? sT[sub][r] : -1e30f;
    }
  }

  float lsum = 0.f;
#pragma unroll
  for (int kc = 0; kc < 2; ++kc) {
#pragma unroll
    for (int s2 = 0; s2 < 2; ++s2) {
      const int sub = kc * 2 + s2;
      const float e0 = exp2f(sT[sub][0]);
      const float e1 = exp2f(sT[sub][1]);
      const float e2 = exp2f(sT[sub][2]);
      const float e3 = exp2f(sT[sub][3]);
      lsum += (e0 + e1) + (e2 + e3);
      uint2 pk;
      pk.x = pk_bf16(e0, e1);
      pk.y = pk_bf16(e2, e3);
      *reinterpret_cast<uint2*>(&pwave[l15 * 40 + s2 * 16 + lg * 4]) = pk;
    }
    const short8 pf = *reinterpret_cast<const short8*>(&pwave[l15 * 40 + lg * 8]);
    __builtin_amdgcn_s_setprio(1);
#pragma unroll
    for (int dt = 0; dt < 4; ++dt) {
      const short8 vf = *reinterpret_cast<const short8*>(
          &Vb_[kc * 2048 + (dt * 16 + l15) * 32 + slg]);
      st.O[dt] = __builtin_amdgcn_mfma_f32_16x16x32_bf16(vf, pf, st.O[dt], 0, 0, 0);
    }
    __builtin_amdgcn_s_setprio(0);
  }
  st.l += lsum;
}

__global__ __launch_bounds__(256, 4) void attn_kernel(
    const u16* __restrict__ Q, const u16* __restrict__ K, const u16* __restrict__ VT,
    const unsigned long long* __restrict__ MB, u16* __restrict__ AO) {
  __shared__ u16 K_lds[2][4096];
  __shared__ u16 V_lds[2][4096];
  __shared__ u16 p_lds[4][16][40];
  __shared__ unsigned actA_s, actB_s;

  const int tid = threadIdx.x;
  const int wid = tid >> 6, lane = tid & 63;
  const int l15 = lane & 15, lg = lane >> 4;

  const int wgid = blockIdx.x;          // 0..1023
  const int x = wgid & 7, s = wgid >> 3;
  const int g = x + 8 * (s >> 5);       // (h,b) group 0..31
  const int qp = s & 31;                // pair 0..31
  const int h = g & 15, b = g >> 4;
  const int qA_t = qp, qB_t = 63 - qp;  // 32-row q-tiles
  const size_t bh_off = ((size_t)(b * 16 + h)) * 2048 * 64;

  if (tid == 0) { actA_s = 0; actB_s = 0; }
  __syncthreads();
  {
    const int ktc = tid & 31, rg = tid >> 5;
    unsigned long long orA = 0, orB = 0;
#pragma unroll
    for (int i = 0; i < 4; ++i) {
      orA |= MB[(size_t)(qA_t * 32 + rg * 4 + i) * 32 + ktc];
      orB |= MB[(size_t)(qB_t * 32 + rg * 4 + i) * 32 + ktc];
    }
    if (orA) atomicOr(&actA_s, 1u << ktc);
    if (orB) atomicOr(&actB_s, 1u << ktc);
  }

  const int sid = wid >> 1;                       // 0 = A, 1 = B
  const int qt = sid ? qB_t : qA_t;
  const int q = qt * 32 + (wid & 1) * 16 + l15;

  AttnState st;
  {
    const short8* qp_ = reinterpret_cast<const short8*>(Q + bh_off + (size_t)q * 64);
    st.qf0 = qp_[lg]; st.qf1 = qp_[4 + lg];
#pragma unroll
    for (int dt = 0; dt < 4; ++dt) st.O[dt] = f32x4{};
    st.l = 0.f;
  }

  const int slg = (lg ^ ((l15 >> 1) & 3)) * 8;

  int offK[2], offV[2], ldsi[2];
#pragma unroll
  for (int p = 0; p < 2; ++p) {
    const int i = wid * 128 + p * 64 + lane;
    const int pc = i >> 8, row = (i >> 2) & 63, lgc = i & 3;
    const int lgs = lgc ^ ((i >> 3) & 3);
    offK[p] = row * 64 + pc * 32 + lgs * 8;
    offV[p] = row * 2048 + pc * 32 + lgs * 8;
    ldsi[p] = (wid * 128 + p * 64) * 8;
  }
  const u16* Kg = K + bh_off;
  const u16* Vg = VT + bh_off;
  u16* pwave = &p_lds[wid][0][0];

  __syncthreads();
  const unsigned actA = actA_s, actB = actB_s;
  const unsigned actW = sid ? actB : actA;
  unsigned rem = actA | actB;
  int buf = 0;

#define STAGE_TILE(bb, ktv)                                        \
  do {                                                             \
    const u16* ksrc_ = Kg + (ktv) * 64 * 64;                       \
    const u16* vsrc_ = Vg + (ktv) * 64;                            \
    _Pragma("unroll") for (int p_ = 0; p_ < 2; ++p_) {             \
      gload_lds16(ksrc_ + offK[p_], &K_lds[bb][ldsi[p_]]);         \
      gload_lds16(vsrc_ + offV[p_], &V_lds[bb][ldsi[p_]]);         \
    }                                                              \
  } while (0)

  if (rem) {
    int kt = __ffs(rem) - 1;
    unsigned long long w_cur = MB[(size_t)q * 32 + kt];
    STAGE_TILE(0, kt);
    __syncthreads();

    while (true) {
      rem &= rem - 1;
      int ktn = -1;
      unsigned long long w_next = 0;
      if (rem) {
        ktn = __ffs(rem) - 1;
        w_next = MB[(size_t)q * 32 + ktn];
        STAGE_TILE(buf ^ 1, ktn);
      }

      if ((actW >> kt) & 1u)
        attn_tile(st, &K_lds[buf][0], &V_lds[buf][0], pwave, w_cur, l15, lg, slg);

      if (ktn < 0) break;
      __syncthreads();
      buf ^= 1;
      kt = ktn;
      w_cur = w_next;
    }
  }
#undef STAGE_TILE

  {
    float lr = st.l;
    lr += __shfl_xor(lr, 16);
    lr += __shfl_xor(lr, 32);
    const float inv = (lr > 0.f) ? (1.0f / lr) : 0.f;
    u16* dst = AO + ((size_t)(b * 2048 + q)) * 1024 + h * 64;
#pragma unroll
    for (int dt = 0; dt < 4; ++dt) {
      uint2 pk;
      pk.x = pk_bf16(st.O[dt][0] * inv, st.O[dt][1] * inv);
      pk.y = pk_bf16(st.O[dt][2] * inv, st.O[dt][3] * inv);
      *reinterpret_cast<uint2*>(dst + dt * 16 + lg * 4) = pk;
    }
  }
}

// ---------------------------------------------------------------- out GEMM
// BK=32 + XCD swizzle + T3 minimum 2-phase double-buffer.
__global__ __launch_bounds__(256) void gemm_out_kernel(
    const u16* __restrict__ A, const u16* __restrict__ BT,
    const float* __restrict__ bo, float* __restrict__ out) {
  __shared__ u16 As[2][128 * 32];
  __shared__ u16 Bs[2][128 * 32];
  const int tid = threadIdx.x;
  const int lane = tid & 63, wid = tid >> 6;
  const int l15 = lane & 15, lg = lane >> 4;
  const int wg = blockIdx.x;            // 256 = 8 XCDs x 32 m
  const int n0 = (wg & 7) * 128;
  const int m0 = (wg >> 3) * 128;
  const int wr = wid >> 1, wc = wid & 1;

  f32x4 acc[4][4] = {};

#define OUT_STAGE(bb, ktv)                                                \
  do {                                                                    \
    _Pragma("unroll") for (int p_ = 0; p_ < 2; ++p_) {                    \
      const int c_ = p_ * 256 + tid;                                      \
      const int r_ = c_ >> 2, ch_ = c_ & 3;                               \
      gload_lds16(A + (size_t)(m0 + r_) * 1024 + (ktv) * 32 + ch_ * 8,    \
                  &As[bb][(p_ * 256 + wid * 64) * 8]);                    \
      gload_lds16(BT + (size_t)(n0 + r_) * 1024 + (ktv) * 32 + ch_ * 8,   \
                  &Bs[bb][(p_ * 256 + wid * 64) * 8]);                    \
    }                                                                     \
  } while (0)

  OUT_STAGE(0, 0);
  __syncthreads();
  int buf = 0;

  for (int kt = 0; kt < 32; ++kt) {
    if (kt < 31) OUT_STAGE(buf ^ 1, kt + 1);
    short8 af[4], bfr[4];
#pragma unroll
    for (int i = 0; i < 4; ++i) {
      af[i] = *reinterpret_cast<const short8*>(&As[buf][(wr * 64 + i * 16 + l15) * 32 + lg * 8]);
      bfr[i] = *reinterpret_cast<const short8*>(&Bs[buf][(wc * 64 + i * 16 + l15) * 32 + lg * 8]);
    }
#pragma unroll
    for (int i = 0; i < 4; ++i)
#pragma unroll
      for (int j = 0; j < 4; ++j)
        acc[i][j] = __builtin_amdgcn_mfma_f32_16x16x32_bf16(bfr[j], af[i], acc[i][j], 0, 0, 0);
    __syncthreads();
    buf ^= 1;
  }
#undef OUT_STAGE

#pragma unroll
  for (int i = 0; i < 4; ++i) {
    const int m = m0 + wr * 64 + i * 16 + l15;
#pragma unroll
    for (int j = 0; j < 4; ++j) {
      const int n = n0 + wc * 64 + j * 16 + lg * 4;
      const float4 b4 = *reinterpret_cast<const float4*>(bo + n);
      float4 o4;
      o4.x = acc[i][j][0] + b4.x;
      o4.y = acc[i][j][1] + b4.y;
      o4.z = acc[i][j][2] + b4.z;
      o4.w = acc[i][j][3] + b4.w;
      *reinterpret_cast<float4*>(out + (size_t)m * 1024 + n) = o4;
    }
  }
}

// ---------------------------------------------------------------- launcher
extern "C" void kernel_launch(void* const* d_in, const int* in_sizes, int n_in,
                              void* d_out, int out_size, void* d_ws, size_t ws_size,
                              hipStream_t stream) {
  (void)in_sizes; (void)n_in; (void)out_size; (void)ws_size;
  const float* hs = (const float*)d_in[0];
  const int* mask = (const int*)d_in[1];
  const float* Wq = (const float*)d_in[2];
  const float* bq = (const float*)d_in[3];
  const float* Wk = (const float*)d_in[4];
  const float* bk = (const float*)d_in[5];
  const float* Wv = (const float*)d_in[6];
  const float* bv = (const float*)d_in[7];
  const float* Wo = (const float*)d_in[8];
  const float* bo = (const float*)d_in[9];
  float* out = (float*)d_out;

  uint8_t* ws = (uint8_t*)d_ws;
  u16* X  = (u16*)(ws);                          // 8 MiB (dead after gemm_qkv)
  u16* WT = (u16*)(ws + ((size_t)8 << 20));      // 8 MiB
  u16* Qb = (u16*)(ws + ((size_t)16 << 20));     // 8 MiB
  u16* Kb = (u16*)(ws + ((size_t)24 << 20));     // 8 MiB
  u16* Vb = (u16*)(ws + ((size_t)32 << 20));     // 8 MiB
  u16* AO = (u16*)(ws + ((size_t)40 << 20));     // 8 MiB
  unsigned long long* MB = (unsigned long long*)(ws + ((size_t)48 << 20));  // 512 KiB
  u16* VbT = X;                                  // reuse X region for V^T

  prep_kernel<<<dim3(24576), dim3(256), 0, stream>>>(hs, mask, Wq, Wk, Wv, Wo, X, WT, MB);
  gemm_qkv_kernel<<<dim3(768), dim3(256), 0, stream>>>(X, WT, bq, bk, bv, Qb, Kb, Vb);
  transpose_v_kernel<<<dim3(1024), dim3(256), 0, stream>>>(Vb, VbT);
  attn_kernel<<<dim3(1024), dim3(256), 0, stream>>>(Qb, Kb, VbT, MB, AO);
  gemm_out_kernel<<<dim3(256), dim3(256), 0, stream>>>(AO, WT + (size_t)3072 * 1024, bo, out);
}

// Round 17
// 133.517 us; speedup vs baseline: 1.0731x; 1.0731x over previous
//
#include <hip/hip_runtime.h>
#include <hip/hip_bf16.h>
#include <stdint.h>

typedef unsigned short u16;
typedef short short8 __attribute__((ext_vector_type(8)));
typedef float f32x4 __attribute__((ext_vector_type(4)));
typedef u16 u16x4 __attribute__((ext_vector_type(4)));

#define SCLOG 0.18033688011112042f  // 0.125 * log2(e)

static __device__ __forceinline__ u16 f2bf(float f) {
  unsigned u = __float_as_uint(f);
  unsigned rnd = 0x7fffu + ((u >> 16) & 1u);
  return (u16)((u + rnd) >> 16);
}

// packed f32x2 -> bf16x2 via HW v_cvt_pk_bf16_f32 (no builtin on gfx950; T12/m240)
static __device__ __forceinline__ unsigned pk_bf16(float a, float b) {
  unsigned r;
  asm("v_cvt_pk_bf16_f32 %0, %1, %2" : "=v"(r) : "v"(a), "v"(b));
  return r;
}

static __device__ __forceinline__ void gload_lds16(const void* g, void* l) {
  __builtin_amdgcn_global_load_lds(
      (const __attribute__((address_space(1))) unsigned int*)g,
      (__attribute__((address_space(3))) unsigned int*)l, 16, 0, 0);
}

// ---------------------------------------------------------------- fused prep
__global__ __launch_bounds__(256) void prep_kernel(
    const float* __restrict__ hs, const int* __restrict__ mask,
    const float* __restrict__ Wq, const float* __restrict__ Wk,
    const float* __restrict__ Wv, const float* __restrict__ Wo,
    u16* __restrict__ X, u16* __restrict__ WT,
    unsigned long long* __restrict__ bits) {
  __shared__ float tile[32][33];
  const int bid = blockIdx.x;
  const int tid = threadIdx.x;
  if (bid < 4096) {
    const int i = bid * 256 + tid;
    const float4 v = reinterpret_cast<const float4*>(hs)[i];
    u16x4 o;
    o[0] = f2bf(v.x); o[1] = f2bf(v.y); o[2] = f2bf(v.z); o[3] = f2bf(v.w);
    reinterpret_cast<u16x4*>(X)[i] = o;
  } else if (bid < 8192) {
    const int B = bid - 4096;
    const int z = B >> 10, y = (B >> 5) & 31, x = B & 31;
    const float* src = (z == 0) ? Wq : (z == 1) ? Wk : (z == 2) ? Wv : Wo;
    u16* dst = WT + (size_t)z * 1024 * 1024;
    const int row0 = y * 32, col0 = x * 32;
    const int tx = tid & 31, ty = tid >> 5;
#pragma unroll
    for (int i = 0; i < 4; ++i)
      tile[ty + i * 8][tx] = src[(size_t)(row0 + ty + i * 8) * 1024 + col0 + tx];
    __syncthreads();
#pragma unroll
    for (int i = 0; i < 4; ++i) {
      const int r = ty + i * 8;
      dst[(size_t)(col0 + r) * 1024 + row0 + tx] = f2bf(tile[tx][r]);
    }
  } else {
    const int gw = (bid - 8192) * 4 + (tid >> 6);
    const int lane = tid & 63;
    const int q = gw >> 5, w = gw & 31;
    const int mv = mask[(size_t)q * 2048 + w * 64 + lane];
    const unsigned long long bal = __ballot(mv != 0);
    if (lane == 0) bits[(size_t)q * 32 + w] = bal;
  }
}

// ---------------------------------------------------------------- GEMM QKV
// BK=32 2-phase structure + XCD-aware block swizzle: each XCD owns 3 WT
// n-panels (L2-resident) and sweeps all 32 m-blocks over them.
__global__ __launch_bounds__(256) void gemm_qkv_kernel(
    const u16* __restrict__ X, const u16* __restrict__ WT,
    const float* __restrict__ bq, const float* __restrict__ bk, const float* __restrict__ bv,
    u16* __restrict__ Qb, u16* __restrict__ Kb, u16* __restrict__ Vb) {
  __shared__ u16 As[128 * 32];
  __shared__ u16 Bs[128 * 32];
  const int tid = threadIdx.x;
  const int lane = tid & 63, wid = tid >> 6;
  const int l15 = lane & 15, lg = lane >> 4;
  const int wg = blockIdx.x;            // 768 = 8 XCDs x (3 n-panels x 32 m)
  const int xcd = wg & 7, idx = wg >> 3;
  const int n0 = (xcd * 3 + (idx >> 5)) * 128;
  const int m0 = (idx & 31) * 128;
  const int wr = wid >> 1, wc = wid & 1;

  f32x4 acc[4][4] = {};

  for (int kt = 0; kt < 32; ++kt) {
    __syncthreads();
#pragma unroll
    for (int p = 0; p < 2; ++p) {
      const int c = p * 256 + tid;
      const int r = c >> 2, ch = c & 3;
      gload_lds16(X + (size_t)(m0 + r) * 1024 + kt * 32 + ch * 8,
                  &As[(p * 256 + wid * 64) * 8]);
      gload_lds16(WT + (size_t)(n0 + r) * 1024 + kt * 32 + ch * 8,
                  &Bs[(p * 256 + wid * 64) * 8]);
    }
    __syncthreads();
    short8 af[4], bfr[4];
#pragma unroll
    for (int i = 0; i < 4; ++i) {
      af[i] = *reinterpret_cast<const short8*>(&As[(wr * 64 + i * 16 + l15) * 32 + lg * 8]);
      bfr[i] = *reinterpret_cast<const short8*>(&Bs[(wc * 64 + i * 16 + l15) * 32 + lg * 8]);
    }
#pragma unroll
    for (int i = 0; i < 4; ++i)
#pragma unroll
      for (int j = 0; j < 4; ++j)
        acc[i][j] = __builtin_amdgcn_mfma_f32_16x16x32_bf16(bfr[j], af[i], acc[i][j], 0, 0, 0);
  }

#pragma unroll
  for (int i = 0; i < 4; ++i) {
    const int m = m0 + wr * 64 + i * 16 + l15;
    const int bb = m >> 11, t = m & 2047;
#pragma unroll
    for (int j = 0; j < 4; ++j) {
      const int n = n0 + wc * 64 + j * 16 + lg * 4;
      const float* bsrc = (n < 1024) ? (bq + n) : (n < 2048) ? (bk + n - 1024) : (bv + n - 2048);
      const float4 b4 = *reinterpret_cast<const float4*>(bsrc);
      const float scl = (n < 1024) ? SCLOG : 1.0f;
      u16* dst = (n < 1024) ? Qb : (n < 2048) ? Kb : Vb;
      const int nl = n & 1023;
      const int hh = nl >> 6, d0 = nl & 63;
      uint2 pk;
      pk.x = pk_bf16((acc[i][j][0] + b4.x) * scl, (acc[i][j][1] + b4.y) * scl);
      pk.y = pk_bf16((acc[i][j][2] + b4.z) * scl, (acc[i][j][3] + b4.w) * scl);
      *reinterpret_cast<uint2*>(dst + ((size_t)(bb * 16 + hh) * 2048 + t) * 64 + d0) = pk;
    }
  }
}

// ------------------------------------------------------------ V transpose
__global__ __launch_bounds__(256) void transpose_v_kernel(const u16* __restrict__ Vb,
                                                          u16* __restrict__ VT) {
  __shared__ u16 tile[64][68];
  const int tid = threadIdx.x;
  const int tt = blockIdx.x & 31;
  const int bh = blockIdx.x >> 5;
  const size_t base = (size_t)bh * 2048 * 64;
  const int t0 = tt * 64;
#pragma unroll
  for (int p = 0; p < 2; ++p) {
    int i = p * 256 + tid;
    int row = i >> 3, ch = i & 7;
    *reinterpret_cast<short8*>(&tile[row][ch * 8]) =
        *reinterpret_cast<const short8*>(Vb + base + (size_t)(t0 + row) * 64 + ch * 8);
  }
  __syncthreads();
#pragma unroll
  for (int p = 0; p < 2; ++p) {
    int i = p * 256 + tid;
    int d = i >> 3, ch = i & 7;
    short8 v;
#pragma unroll
    for (int j = 0; j < 8; ++j) v[j] = tile[ch * 8 + j][d];
    *reinterpret_cast<short8*>(VT + base + (size_t)d * 2048 + t0 + ch * 8) = v;
  }
}

// ---------------------------------------------------------------- attention
// (R10/R12 version — frozen session optimum. Max-free softmax, 4 waves/block,
// paired 32-row q-tiles, double-buffered LDS staging, grid 1024.)
struct AttnState {
  f32x4 O[4];
  float l;        // per-lane partial (reduced at epilogue)
  short8 qf0, qf1;
};

static __device__ __forceinline__ void attn_tile(
    AttnState& st, const u16* __restrict__ Kb_, const u16* __restrict__ Vb_,
    u16* __restrict__ pwave, unsigned long long w,
    int l15, int lg, int slg) {
  f32x4 sT[4] = {};
  __builtin_amdgcn_s_setprio(1);
#pragma unroll
  for (int dc = 0; dc < 2; ++dc) {
    const short8 qv = dc ? st.qf1 : st.qf0;
#pragma unroll
    for (int sub = 0; sub < 4; ++sub) {
      const short8 kf = *reinterpret_cast<const short8*>(
          &Kb_[dc * 2048 + (sub * 16 + l15) * 32 + slg]);
      sT[sub] = __builtin_amdgcn_mfma_f32_16x16x32_bf16(kf, qv, sT[sub], 0, 0, 0);
    }
  }
  __builtin_amdgcn_s_setprio(0);

  if (!__all(w == ~0ull)) {
    const unsigned mlo = (unsigned)w, mhi = (unsigned)(w >> 32);
#pragma unroll
    for (int sub = 0; sub < 4; ++sub) {
      const unsigned f = ((sub & 2) ? mhi : mlo) >> ((sub & 1) * 16 + lg * 4);
#pragma unroll
      for (int r = 0; r < 4; ++r)
        sT[sub][r] = ((f >> r) & 1u) ? sT[sub][r] : -1e30f;
    }
  }

  float lsum = 0.f;
#pragma unroll
  for (int kc = 0; kc < 2; ++kc) {
#pragma unroll
    for (int s2 = 0; s2 < 2; ++s2) {
      const int sub = kc * 2 + s2;
      const float e0 = exp2f(sT[sub][0]);
      const float e1 = exp2f(sT[sub][1]);
      const float e2 = exp2f(sT[sub][2]);
      const float e3 = exp2f(sT[sub][3]);
      lsum += (e0 + e1) + (e2 + e3);
      uint2 pk;
      pk.x = pk_bf16(e0, e1);
      pk.y = pk_bf16(e2, e3);
      *reinterpret_cast<uint2*>(&pwave[l15 * 40 + s2 * 16 + lg * 4]) = pk;
    }
    const short8 pf = *reinterpret_cast<const short8*>(&pwave[l15 * 40 + lg * 8]);
    __builtin_amdgcn_s_setprio(1);
#pragma unroll
    for (int dt = 0; dt < 4; ++dt) {
      const short8 vf = *reinterpret_cast<const short8*>(
          &Vb_[kc * 2048 + (dt * 16 + l15) * 32 + slg]);
      st.O[dt] = __builtin_amdgcn_mfma_f32_16x16x32_bf16(vf, pf, st.O[dt], 0, 0, 0);
    }
    __builtin_amdgcn_s_setprio(0);
  }
  st.l += lsum;
}

__global__ __launch_bounds__(256, 4) void attn_kernel(
    const u16* __restrict__ Q, const u16* __restrict__ K, const u16* __restrict__ VT,
    const unsigned long long* __restrict__ MB, u16* __restrict__ AO) {
  __shared__ u16 K_lds[2][4096];
  __shared__ u16 V_lds[2][4096];
  __shared__ u16 p_lds[4][16][40];
  __shared__ unsigned actA_s, actB_s;

  const int tid = threadIdx.x;
  const int wid = tid >> 6, lane = tid & 63;
  const int l15 = lane & 15, lg = lane >> 4;

  const int wgid = blockIdx.x;          // 0..1023
  const int x = wgid & 7, s = wgid >> 3;
  const int g = x + 8 * (s >> 5);       // (h,b) group 0..31
  const int qp = s & 31;                // pair 0..31
  const int h = g & 15, b = g >> 4;
  const int qA_t = qp, qB_t = 63 - qp;  // 32-row q-tiles
  const size_t bh_off = ((size_t)(b * 16 + h)) * 2048 * 64;

  if (tid == 0) { actA_s = 0; actB_s = 0; }
  __syncthreads();
  {
    const int ktc = tid & 31, rg = tid >> 5;
    unsigned long long orA = 0, orB = 0;
#pragma unroll
    for (int i = 0; i < 4; ++i) {
      orA |= MB[(size_t)(qA_t * 32 + rg * 4 + i) * 32 + ktc];
      orB |= MB[(size_t)(qB_t * 32 + rg * 4 + i) * 32 + ktc];
    }
    if (orA) atomicOr(&actA_s, 1u << ktc);
    if (orB) atomicOr(&actB_s, 1u << ktc);
  }

  const int sid = wid >> 1;                       // 0 = A, 1 = B
  const int qt = sid ? qB_t : qA_t;
  const int q = qt * 32 + (wid & 1) * 16 + l15;

  AttnState st;
  {
    const short8* qp_ = reinterpret_cast<const short8*>(Q + bh_off + (size_t)q * 64);
    st.qf0 = qp_[lg]; st.qf1 = qp_[4 + lg];
#pragma unroll
    for (int dt = 0; dt < 4; ++dt) st.O[dt] = f32x4{};
    st.l = 0.f;
  }

  const int slg = (lg ^ ((l15 >> 1) & 3)) * 8;

  int offK[2], offV[2], ldsi[2];
#pragma unroll
  for (int p = 0; p < 2; ++p) {
    const int i = wid * 128 + p * 64 + lane;
    const int pc = i >> 8, row = (i >> 2) & 63, lgc = i & 3;
    const int lgs = lgc ^ ((i >> 3) & 3);
    offK[p] = row * 64 + pc * 32 + lgs * 8;
    offV[p] = row * 2048 + pc * 32 + lgs * 8;
    ldsi[p] = (wid * 128 + p * 64) * 8;
  }
  const u16* Kg = K + bh_off;
  const u16* Vg = VT + bh_off;
  u16* pwave = &p_lds[wid][0][0];

  __syncthreads();
  const unsigned actA = actA_s, actB = actB_s;
  const unsigned actW = sid ? actB : actA;
  unsigned rem = actA | actB;
  int buf = 0;

#define STAGE_TILE(bb, ktv)                                        \
  do {                                                             \
    const u16* ksrc_ = Kg + (ktv) * 64 * 64;                       \
    const u16* vsrc_ = Vg + (ktv) * 64;                            \
    _Pragma("unroll") for (int p_ = 0; p_ < 2; ++p_) {             \
      gload_lds16(ksrc_ + offK[p_], &K_lds[bb][ldsi[p_]]);         \
      gload_lds16(vsrc_ + offV[p_], &V_lds[bb][ldsi[p_]]);         \
    }                                                              \
  } while (0)

  if (rem) {
    int kt = __ffs(rem) - 1;
    unsigned long long w_cur = MB[(size_t)q * 32 + kt];
    STAGE_TILE(0, kt);
    __syncthreads();

    while (true) {
      rem &= rem - 1;
      int ktn = -1;
      unsigned long long w_next = 0;
      if (rem) {
        ktn = __ffs(rem) - 1;
        w_next = MB[(size_t)q * 32 + ktn];
        STAGE_TILE(buf ^ 1, ktn);
      }

      if ((actW >> kt) & 1u)
        attn_tile(st, &K_lds[buf][0], &V_lds[buf][0], pwave, w_cur, l15, lg, slg);

      if (ktn < 0) break;
      __syncthreads();
      buf ^= 1;
      kt = ktn;
      w_cur = w_next;
    }
  }
#undef STAGE_TILE

  {
    float lr = st.l;
    lr += __shfl_xor(lr, 16);
    lr += __shfl_xor(lr, 32);
    const float inv = (lr > 0.f) ? (1.0f / lr) : 0.f;
    u16* dst = AO + ((size_t)(b * 2048 + q)) * 1024 + h * 64;
#pragma unroll
    for (int dt = 0; dt < 4; ++dt) {
      uint2 pk;
      pk.x = pk_bf16(st.O[dt][0] * inv, st.O[dt][1] * inv);
      pk.y = pk_bf16(st.O[dt][2] * inv, st.O[dt][3] * inv);
      *reinterpret_cast<uint2*>(dst + dt * 16 + lg * 4) = pk;
    }
  }
}

// ---------------------------------------------------------------- out GEMM
// BK=32 2-phase + XCD swizzle: one n-panel per XCD (Wo panel L2-pinned).
__global__ __launch_bounds__(256) void gemm_out_kernel(
    const u16* __restrict__ A, const u16* __restrict__ BT,
    const float* __restrict__ bo, float* __restrict__ out) {
  __shared__ u16 As[128 * 32];
  __shared__ u16 Bs[128 * 32];
  const int tid = threadIdx.x;
  const int lane = tid & 63, wid = tid >> 6;
  const int l15 = lane & 15, lg = lane >> 4;
  const int wg = blockIdx.x;            // 256 = 8 XCDs x 32 m
  const int n0 = (wg & 7) * 128;
  const int m0 = (wg >> 3) * 128;
  const int wr = wid >> 1, wc = wid & 1;

  f32x4 acc[4][4] = {};

  for (int kt = 0; kt < 32; ++kt) {
    __syncthreads();
#pragma unroll
    for (int p = 0; p < 2; ++p) {
      const int c = p * 256 + tid;
      const int r = c >> 2, ch = c & 3;
      gload_lds16(A + (size_t)(m0 + r) * 1024 + kt * 32 + ch * 8,
                  &As[(p * 256 + wid * 64) * 8]);
      gload_lds16(BT + (size_t)(n0 + r) * 1024 + kt * 32 + ch * 8,
                  &Bs[(p * 256 + wid * 64) * 8]);
    }
    __syncthreads();
    short8 af[4], bfr[4];
#pragma unroll
    for (int i = 0; i < 4; ++i) {
      af[i] = *reinterpret_cast<const short8*>(&As[(wr * 64 + i * 16 + l15) * 32 + lg * 8]);
      bfr[i] = *reinterpret_cast<const short8*>(&Bs[(wc * 64 + i * 16 + l15) * 32 + lg * 8]);
    }
#pragma unroll
    for (int i = 0; i < 4; ++i)
#pragma unroll
      for (int j = 0; j < 4; ++j)
        acc[i][j] = __builtin_amdgcn_mfma_f32_16x16x32_bf16(bfr[j], af[i], acc[i][j], 0, 0, 0);
  }

#pragma unroll
  for (int i = 0; i < 4; ++i) {
    const int m = m0 + wr * 64 + i * 16 + l15;
#pragma unroll
    for (int j = 0; j < 4; ++j) {
      const int n = n0 + wc * 64 + j * 16 + lg * 4;
      const float4 b4 = *reinterpret_cast<const float4*>(bo + n);
      float4 o4;
      o4.x = acc[i][j][0] + b4.x;
      o4.y = acc[i][j][1] + b4.y;
      o4.z = acc[i][j][2] + b4.z;
      o4.w = acc[i][j][3] + b4.w;
      *reinterpret_cast<float4*>(out + (size_t)m * 1024 + n) = o4;
    }
  }
}

// ---------------------------------------------------------------- launcher
extern "C" void kernel_launch(void* const* d_in, const int* in_sizes, int n_in,
                              void* d_out, int out_size, void* d_ws, size_t ws_size,
                              hipStream_t stream) {
  (void)in_sizes; (void)n_in; (void)out_size; (void)ws_size;
  const float* hs = (const float*)d_in[0];
  const int* mask = (const int*)d_in[1];
  const float* Wq = (const float*)d_in[2];
  const float* bq = (const float*)d_in[3];
  const float* Wk = (const float*)d_in[4];
  const float* bk = (const float*)d_in[5];
  const float* Wv = (const float*)d_in[6];
  const float* bv = (const float*)d_in[7];
  const float* Wo = (const float*)d_in[8];
  const float* bo = (const float*)d_in[9];
  float* out = (float*)d_out;

  uint8_t* ws = (uint8_t*)d_ws;
  u16* X  = (u16*)(ws);                          // 8 MiB (dead after gemm_qkv)
  u16* WT = (u16*)(ws + ((size_t)8 << 20));      // 8 MiB
  u16* Qb = (u16*)(ws + ((size_t)16 << 20));     // 8 MiB
  u16* Kb = (u16*)(ws + ((size_t)24 << 20));     // 8 MiB
  u16* Vb = (u16*)(ws + ((size_t)32 << 20));     // 8 MiB
  u16* AO = (u16*)(ws + ((size_t)40 << 20));     // 8 MiB
  unsigned long long* MB = (unsigned long long*)(ws + ((size_t)48 << 20));  // 512 KiB
  u16* VbT = X;                                  // reuse X region for V^T

  prep_kernel<<<dim3(24576), dim3(256), 0, stream>>>(hs, mask, Wq, Wk, Wv, Wo, X, WT, MB);
  gemm_qkv_kernel<<<dim3(768), dim3(256), 0, stream>>>(X, WT, bq, bk, bv, Qb, Kb, Vb);
  transpose_v_kernel<<<dim3(1024), dim3(256), 0, stream>>>(Vb, VbT);
  attn_kernel<<<dim3(1024), dim3(256), 0, stream>>>(Qb, Kb, VbT, MB, AO);
  gemm_out_kernel<<<dim3(256), dim3(256), 0, stream>>>(AO, WT + (size_t)3072 * 1024, bo, out);
}